// Round 10
// baseline (273.234 us; speedup 1.0000x reference)
//
#include <hip/hip_runtime.h>
#include <hip/hip_bf16.h>
#include <math.h>

typedef __bf16 bf16;
typedef __bf16 bf16x4 __attribute__((ext_vector_type(4)));
typedef __bf16 bf16x8 __attribute__((ext_vector_type(8)));
typedef float f32x4 __attribute__((ext_vector_type(4)));
typedef float f32x16 __attribute__((ext_vector_type(16)));
typedef unsigned int uint32x4 __attribute__((ext_vector_type(4)));

// ---------------------------------------------------------------- helpers
__device__ __forceinline__ void gload_lds16(const void* g, void* l) {
  __builtin_amdgcn_global_load_lds(
      (const __attribute__((address_space(1))) void*)g,
      (__attribute__((address_space(3))) void*)l, 16, 0, 0);
}

__device__ __forceinline__ unsigned int packbf(float a, float b) {
  union { bf16 h[2]; unsigned int u; } x;
  x.h[0] = (bf16)a; x.h[1] = (bf16)b;
  return x.u;
}

// ---------------------------------------------------------------- fused f32 -> bf16 (all tensors, one launch)
__global__ void cvt_all(const float* __restrict__ x,  const float* __restrict__ Wq,
                        const float* __restrict__ Wk, const float* __restrict__ Wv,
                        const float* __restrict__ Wo,
                        bf16* __restrict__ xb, bf16* __restrict__ wqkv, bf16* __restrict__ wob,
                        float qscale) {
  const int stride = gridDim.x * blockDim.x;
  const int total4 = 4718592;  // 18,874,368 / 4
  for (int i = blockIdx.x * blockDim.x + threadIdx.x; i < total4; i += stride) {
    const size_t e = (size_t)i * 4;
    const float* src; bf16* dst; size_t off; float sc = 1.f;
    if (e < 8388608)       { src = x;  dst = xb;            off = e; }
    else if (e < 12582912) { src = Wq; dst = wqkv;          off = e - 8388608; sc = qscale; }
    else if (e < 13631488) { src = Wk; dst = wqkv + 4194304; off = e - 12582912; }
    else if (e < 14680064) { src = Wv; dst = wqkv + 5242880; off = e - 13631488; }
    else                   { src = Wo; dst = wob;           off = e - 14680064; }
    float4 v = *(const float4*)(src + off);
    bf16x4 o;
    o[0] = (bf16)(v.x * sc); o[1] = (bf16)(v.y * sc);
    o[2] = (bf16)(v.z * sc); o[3] = (bf16)(v.w * sc);
    *(bf16x4*)(dst + off) = o;
  }
}

// ---------------------------------------------------------------- 128x128 NT GEMM (R5 skeleton + depth-1 counted vmcnt)
// C[M,N] = A[M,K] @ B[N,K]^T. MODE 0: f32 C (stride Nst). MODE 1: QKV routing.
// 2 bufs x 16KB = 32KB LDS (keeps ~5 blocks/CU). k-chunk-major [4 kc][128 r][16B]:
// linear gload dest (ci*16) and conflict-free ds_read (fq*2048 + r*16).
template <int MODE>
__global__ __launch_bounds__(256)
void gemm128(const bf16* __restrict__ A, const bf16* __restrict__ B,
             float* __restrict__ Cf, bf16* __restrict__ Qb, bf16* __restrict__ Kb,
             bf16* __restrict__ Vtb, int K, int Nst) {
  __shared__ __align__(16) char smem[32768];

  const int tid  = threadIdx.x;
  const int lane = tid & 63, w = tid >> 6;
  const int wr   = w >> 1, wc = w & 1;          // 2x2 wave grid, 64x64 per wave
  const int fr   = lane & 15, fq = lane >> 4;
  const int brow = blockIdx.y, bcol = blockIdx.x;

  f32x4 acc[4][4] = {};

  const bf16* Ab = A + (size_t)brow * 128 * K;
  const bf16* Bb = B + (size_t)bcol * 128 * K;
  const int NT = K >> 5;

  auto stage = [&](int t, int buf) {
    char* base = smem + buf * 16384;
#pragma unroll
    for (int i = 0; i < 2; ++i) {
      const int ci = i * 256 + tid;        // 0..511: kc = ci>>7, row = ci&127
      const int kc = ci >> 7, row = ci & 127;
      // dest offset kc*2048 + row*16 == ci*16 (linear in lane order)
      gload_lds16(Ab + (size_t)row * K + t * 32 + kc * 8, base + i * 4096 + w * 1024);
      gload_lds16(Bb + (size_t)row * K + t * 32 + kc * 8, base + 8192 + i * 4096 + w * 1024);
    }
  };

  stage(0, 0);
  for (int t = 0; t < NT; ++t) {
    const int buf = t & 1;
    if (t + 1 < NT) {
      stage(t + 1, buf ^ 1);
      asm volatile("s_waitcnt vmcnt(4)" ::: "memory");   // tile t resident; t+1 in flight
    } else {
      asm volatile("s_waitcnt vmcnt(0)" ::: "memory");
    }
    __builtin_amdgcn_s_barrier();

    const char* pA = smem + buf * 16384;
    const char* pB = pA + 8192;
    bf16x8 af[4], bfr[4];
#pragma unroll
    for (int i = 0; i < 4; ++i) {
      af[i]  = *(const bf16x8*)(pA + fq * 2048 + (wr * 64 + i * 16 + fr) * 16);
      bfr[i] = *(const bf16x8*)(pB + fq * 2048 + (wc * 64 + i * 16 + fr) * 16);
    }
#pragma unroll
    for (int mi = 0; mi < 4; ++mi)
#pragma unroll
      for (int ni = 0; ni < 4; ++ni)
        acc[mi][ni] = __builtin_amdgcn_mfma_f32_16x16x32_bf16(af[mi], bfr[ni], acc[mi][ni], 0, 0, 0);
    __builtin_amdgcn_s_barrier();
  }

  // ---- epilogue: D layout row=(lane>>4)*4+j, col=lane&15
  const int r0 = brow * 128 + wr * 64 + fq * 4;
  const int c0 = bcol * 128 + wc * 64 + fr;
#pragma unroll
  for (int mi = 0; mi < 4; ++mi)
#pragma unroll
    for (int ni = 0; ni < 4; ++ni)
#pragma unroll
      for (int j = 0; j < 4; ++j) {
        const int r = r0 + mi * 16 + j;
        const int c = c0 + ni * 16;
        const float v = acc[mi][ni][j];
        if constexpr (MODE == 0) {
          Cf[(size_t)r * Nst + c] = v;
        } else {
          if (c < 2048)       Qb[(size_t)r * 2048 + c] = (bf16)v;
          else if (c < 2560)  Kb[(size_t)r * 512 + (c - 2048)] = (bf16)v;
          else                Vtb[(size_t)(c - 2560) * 4096 + r] = (bf16)v;
        }
      }
}

// ---------------------------------------------------------------- flash attention (causal GQA)
// 32x32 MFMA, swapped operands: S^T = K*Q^T (lane owns q=lane&31), O^T = V^T*P^T.
__global__ __launch_bounds__(256, 2)
void attn_fwd(const bf16* __restrict__ Q, const bf16* __restrict__ Kg_,
              const bf16* __restrict__ Vt, bf16* __restrict__ AO) {
  const int T = 2048, C = 2048, KVD = 512, MTOK = 4096;
  const int bid = blockIdx.x;
  const int qt  = (bid < 256) ? (15 - (bid >> 5)) : ((bid >> 5) - 8);  // snake balance
  const int sub = bid & 31;
  const int h = sub & 15, b = sub >> 4;
  const int kvh = h >> 2;
  const int lane = threadIdx.x & 63, w = threadIdx.x >> 6;
  const int hi = lane >> 5, lo = lane & 31;

  __shared__ __align__(16) char smem[65536];
  char* sK  = smem;          // 2 bufs x [64 rows][256 B], chunk-XOR (r&7)
  char* sVt = smem + 32768;  // 2 bufs x [128 rows][128 B], chunk-XOR (r&7)

  const bf16* Qg = Q   + (size_t)b * T * C + (size_t)h * 128;
  const bf16* Kg = Kg_ + (size_t)b * T * KVD + (size_t)kvh * 128;
  const bf16* Vg = Vt  + (size_t)kvh * 128 * MTOK + (size_t)b * T;

  const int q0 = qt * 128;
  const int qw = q0 + w * 32;

  bf16x8 qf[8];
#pragma unroll
  for (int ks = 0; ks < 8; ++ks)
    qf[ks] = *(const bf16x8*)(Qg + (size_t)(qw + lo) * C + ks * 16 + hi * 8);

  f32x16 ot[4] = {};
  float mstat = -INFINITY, lstat = 0.f;

  const int nt = 2 * qt + 2;

  auto stage = [&](int t, int buf) {
#pragma unroll
    for (int i = 0; i < 4; ++i) {
      const int ci = i * 256 + threadIdx.x;
      const int rk = ci >> 4, ck = ci & 15;
      gload_lds16(Kg + (size_t)(t * 64 + rk) * KVD + ((ck ^ (rk & 7)) * 8),
                  sK + buf * 16384 + i * 4096 + w * 1024);
      const int rv = ci >> 3, cv = ci & 7;
      gload_lds16(Vg + (size_t)rv * MTOK + t * 64 + ((cv ^ (rv & 7)) * 8),
                  sVt + buf * 16384 + i * 4096 + w * 1024);
    }
  };

  auto compute = [&](int t, int buf) {
    const int kv0 = t * 64;
    if (kv0 > qw + 31) return;
    const char* kb = sK + buf * 16384;
    const char* vb = sVt + buf * 16384;

    f32x16 sa[2] = {};
    __builtin_amdgcn_s_setprio(1);
#pragma unroll
    for (int ks = 0; ks < 8; ++ks) {
#pragma unroll
      for (int nb = 0; nb < 2; ++nb) {
        const int r = nb * 32 + lo;
        bf16x8 kf = *(const bf16x8*)(kb + (r * 256 + (((ks * 2 + hi) ^ (r & 7)) * 16)));
        sa[nb] = __builtin_amdgcn_mfma_f32_32x32x16_bf16(kf, qf[ks], sa[nb], 0, 0, 0);
      }
    }
    __builtin_amdgcn_s_setprio(0);
    if (kv0 + 63 > qw) {
      const int qg = qw + lo;
#pragma unroll
      for (int nb = 0; nb < 2; ++nb)
#pragma unroll
        for (int r = 0; r < 16; ++r) {
          const int kvg = kv0 + nb * 32 + (r & 3) + 8 * (r >> 2) + 4 * hi;
          if (kvg > qg) sa[nb][r] = -1e30f;
        }
    }
    float pm = -INFINITY;
#pragma unroll
    for (int nb = 0; nb < 2; ++nb)
#pragma unroll
      for (int r = 0; r < 16; ++r) pm = fmaxf(pm, sa[nb][r]);
    pm = fmaxf(pm, __shfl_xor(pm, 32));

    if (__any(pm > mstat + 8.f)) {           // defer-max (T13)
      const float mn = fmaxf(mstat, pm);
      const float rs = __expf(mstat - mn);
      mstat = mn;
      lstat *= rs;
#pragma unroll
      for (int db = 0; db < 4; ++db)
#pragma unroll
        for (int r = 0; r < 16; ++r) ot[db][r] *= rs;
    }

    float ls = 0.f;
    unsigned int pw[2][8];
#pragma unroll
    for (int nb = 0; nb < 2; ++nb)
#pragma unroll
      for (int j = 0; j < 8; ++j) {
        const float e0 = __expf(sa[nb][2 * j]     - mstat);
        const float e1 = __expf(sa[nb][2 * j + 1] - mstat);
        ls += e0 + e1;
        pw[nb][j] = packbf(e0, e1);
      }
    ls += __shfl_xor(ls, 32);
    lstat += ls;

#pragma unroll
    for (int nb = 0; nb < 2; ++nb) {
      unsigned int pj[8];
#pragma unroll
      for (int j = 0; j < 8; ++j) pj[j] = __shfl_xor(pw[nb][j], 32);
      __builtin_amdgcn_s_setprio(1);
#pragma unroll
      for (int half = 0; half < 2; ++half) {
        const int x = half * 4;
        uint32x4 bw;
        bw[0] = hi ? pj[x + 2] : pw[nb][x + 0];
        bw[1] = hi ? pj[x + 3] : pw[nb][x + 1];
        bw[2] = hi ? pw[nb][x + 2] : pj[x + 0];
        bw[3] = hi ? pw[nb][x + 3] : pj[x + 1];
        const bf16x8 pb = __builtin_bit_cast(bf16x8, bw);
        const int ks = nb * 2 + half;
#pragma unroll
        for (int db = 0; db < 4; ++db) {
          const int rv = db * 32 + lo;
          bf16x8 vf = *(const bf16x8*)(vb + (rv * 128 + (((ks * 2 + hi) ^ (rv & 7)) * 16)));
          ot[db] = __builtin_amdgcn_mfma_f32_32x32x16_bf16(vf, pb, ot[db], 0, 0, 0);
        }
      }
      __builtin_amdgcn_s_setprio(0);
    }
  };

  stage(0, 0);
  for (int t = 0; t < nt - 1; ++t) {
    stage(t + 1, (t + 1) & 1);
    asm volatile("s_waitcnt vmcnt(8)" ::: "memory");
    __builtin_amdgcn_s_barrier();
    compute(t, t & 1);
    __builtin_amdgcn_s_barrier();
  }
  asm volatile("s_waitcnt vmcnt(0)" ::: "memory");
  __builtin_amdgcn_s_barrier();
  compute(nt - 1, (nt - 1) & 1);

  __syncthreads();
  char* sO = smem;
  const float inv = 1.f / lstat;
  const int lq = w * 32 + lo;
#pragma unroll
  for (int db = 0; db < 4; ++db) {
#pragma unroll
    for (int j = 0; j < 8; ++j) {
      const int r = 2 * j;
      const int d = db * 32 + (r & 3) + 8 * (r >> 2) + 4 * hi;
      const unsigned int pv = packbf(ot[db][r] * inv, ot[db][r + 1] * inv);
      *(unsigned int*)(sO + (lq * 256 + ((2 * d) ^ (16 * (lq & 7))))) = pv;
    }
  }
  __syncthreads();
  bf16* Og = AO + (size_t)b * T * C + (size_t)h * 128;
#pragma unroll
  for (int i = 0; i < 8; ++i) {
    const int cid = i * 256 + threadIdx.x;
    const int rq = cid >> 4, c = cid & 15;
    bf16x8 vv = *(const bf16x8*)(sO + (rq * 256 + ((c * 16) ^ (16 * (rq & 7)))));
    *(bf16x8*)(Og + (size_t)(q0 + rq) * C + c * 8) = vv;
  }
}

// ---------------------------------------------------------------- launch
extern "C" void kernel_launch(void* const* d_in, const int* in_sizes, int n_in,
                              void* d_out, int out_size, void* d_ws, size_t ws_size,
                              hipStream_t stream) {
  const float* x  = (const float*)d_in[0];
  const float* Wq = (const float*)d_in[1];
  const float* Wk = (const float*)d_in[2];
  const float* Wv = (const float*)d_in[3];
  const float* Wo = (const float*)d_in[4];
  float* out = (float*)d_out;

  char* ws = (char*)d_ws;
  bf16* xb   = (bf16*)(ws);                   // 16,777,216 B
  bf16* wqkv = (bf16*)(ws + 16777216);        // 12,582,912  [3072][2048]
  bf16* wob  = (bf16*)(ws + 29360128);        //  8,388,608
  bf16* Qb   = (bf16*)(ws + 37748736);        // 16,777,216
  bf16* Kb   = (bf16*)(ws + 54525952);        //  4,194,304
  bf16* Vtb  = (bf16*)(ws + 58720256);        //  4,194,304  ([512][4096])
  bf16* AOb  = (bf16*)(ws + 62914560);        // 16,777,216

  const float scale = 0.08838834764831845f;   // 128^-0.5, folded into Wq
  cvt_all<<<2048, 256, 0, stream>>>(x, Wq, Wk, Wv, Wo, xb, wqkv, wob, scale);

  gemm128<1><<<dim3(24, 32), 256, 0, stream>>>(xb, wqkv, nullptr, Qb, Kb, Vtb, 2048, 0);

  attn_fwd<<<512, 256, 0, stream>>>(Qb, Kb, Vtb, AOb);

  gemm128<0><<<dim3(16, 32), 256, 0, stream>>>(AOb, wob, out, nullptr, nullptr, nullptr, 2048, 2048);
}

// Round 11
// 194.759 us; speedup vs baseline: 1.4029x; 1.4029x over previous
//
#include <hip/hip_runtime.h>
#include <hip/hip_bf16.h>
#include <math.h>

typedef __bf16 bf16;
typedef __bf16 bf16x4 __attribute__((ext_vector_type(4)));
typedef __bf16 bf16x8 __attribute__((ext_vector_type(8)));
typedef float f32x4 __attribute__((ext_vector_type(4)));
typedef float f32x16 __attribute__((ext_vector_type(16)));
typedef unsigned int uint32x4 __attribute__((ext_vector_type(4)));

// ---------------------------------------------------------------- helpers
__device__ __forceinline__ void gload_lds16(const void* g, void* l) {
  __builtin_amdgcn_global_load_lds(
      (const __attribute__((address_space(1))) void*)g,
      (__attribute__((address_space(3))) void*)l, 16, 0, 0);
}

__device__ __forceinline__ unsigned int packbf(float a, float b) {
  union { bf16 h[2]; unsigned int u; } x;
  x.h[0] = (bf16)a; x.h[1] = (bf16)b;
  return x.u;
}

// ---------------------------------------------------------------- fused f32 -> bf16 (all tensors, one launch)
__global__ void cvt_all(const float* __restrict__ x,  const float* __restrict__ Wq,
                        const float* __restrict__ Wk, const float* __restrict__ Wv,
                        const float* __restrict__ Wo,
                        bf16* __restrict__ xb, bf16* __restrict__ wqkv, bf16* __restrict__ wob,
                        float qscale) {
  const int stride = gridDim.x * blockDim.x;
  const int total4 = 4718592;  // 18,874,368 / 4
  for (int i = blockIdx.x * blockDim.x + threadIdx.x; i < total4; i += stride) {
    const size_t e = (size_t)i * 4;
    const float* src; bf16* dst; size_t off; float sc = 1.f;
    if (e < 8388608)       { src = x;  dst = xb;            off = e; }
    else if (e < 12582912) { src = Wq; dst = wqkv;          off = e - 8388608; sc = qscale; }
    else if (e < 13631488) { src = Wk; dst = wqkv + 4194304; off = e - 12582912; }
    else if (e < 14680064) { src = Wv; dst = wqkv + 5242880; off = e - 13631488; }
    else                   { src = Wo; dst = wob;           off = e - 14680064; }
    float4 v = *(const float4*)(src + off);
    bf16x4 o;
    o[0] = (bf16)(v.x * sc); o[1] = (bf16)(v.y * sc);
    o[2] = (bf16)(v.z * sc); o[3] = (bf16)(v.w * sc);
    *(bf16x4*)(dst + off) = o;
  }
}

// ---------------------------------------------------------------- 128x128 NT GEMM
// R5 skeleton (coalesced 64B-segment staging, row-major [128][32] LDS) +
// depth-1 counted-vmcnt prefetch (2 bufs x 16KB). MODE 0: f32 C. MODE 1: QKV routing.
template <int MODE>
__global__ __launch_bounds__(256)
void gemm128(const bf16* __restrict__ A, const bf16* __restrict__ B,
             float* __restrict__ Cf, bf16* __restrict__ Qb, bf16* __restrict__ Kb,
             bf16* __restrict__ Vtb, int K, int Nst) {
  __shared__ __align__(16) char smem[32768];

  const int tid  = threadIdx.x;
  const int lane = tid & 63, w = tid >> 6;
  const int wr   = w >> 1, wc = w & 1;          // 2x2 wave grid, 64x64 per wave
  const int fr   = lane & 15, fq = lane >> 4;
  const int brow = blockIdx.y, bcol = blockIdx.x;

  f32x4 acc[4][4] = {};

  const bf16* Ab = A + (size_t)brow * 128 * K;
  const bf16* Bb = B + (size_t)bcol * 128 * K;
  const int NT = K >> 5;

  const int srow = w * 32 + (lane >> 2);   // staging row within tile
  const int skc  = (lane & 3) * 8;         // staging k-chunk (8 bf16 = 16B)

  auto stage = [&](int t, int buf) {
    char* base = smem + buf * 16384;
    gload_lds16(Ab + (size_t)srow * K + t * 32 + skc,        base + w * 2048);
    gload_lds16(Ab + (size_t)(srow + 16) * K + t * 32 + skc, base + w * 2048 + 1024);
    gload_lds16(Bb + (size_t)srow * K + t * 32 + skc,        base + 8192 + w * 2048);
    gload_lds16(Bb + (size_t)(srow + 16) * K + t * 32 + skc, base + 8192 + w * 2048 + 1024);
  };

  stage(0, 0);
  for (int t = 0; t < NT; ++t) {
    const int buf = t & 1;
    if (t + 1 < NT) {
      stage(t + 1, buf ^ 1);
      asm volatile("s_waitcnt vmcnt(4)" ::: "memory");   // tile t resident; t+1 in flight
    } else {
      asm volatile("s_waitcnt vmcnt(0)" ::: "memory");
    }
    __builtin_amdgcn_s_barrier();

    const char* pA = smem + buf * 16384;
    const char* pB = pA + 8192;
    bf16x8 af[4], bfr[4];
#pragma unroll
    for (int i = 0; i < 4; ++i) {
      af[i]  = *(const bf16x8*)(pA + ((wr * 64 + i * 16 + fr) * 64 + fq * 16));
      bfr[i] = *(const bf16x8*)(pB + ((wc * 64 + i * 16 + fr) * 64 + fq * 16));
    }
#pragma unroll
    for (int mi = 0; mi < 4; ++mi)
#pragma unroll
      for (int ni = 0; ni < 4; ++ni)
        acc[mi][ni] = __builtin_amdgcn_mfma_f32_16x16x32_bf16(af[mi], bfr[ni], acc[mi][ni], 0, 0, 0);
    __builtin_amdgcn_s_barrier();
  }

  // ---- epilogue: D layout row=(lane>>4)*4+j, col=lane&15
  const int r0 = brow * 128 + wr * 64 + fq * 4;
  const int c0 = bcol * 128 + wc * 64 + fr;
#pragma unroll
  for (int mi = 0; mi < 4; ++mi)
#pragma unroll
    for (int ni = 0; ni < 4; ++ni)
#pragma unroll
      for (int j = 0; j < 4; ++j) {
        const int r = r0 + mi * 16 + j;
        const int c = c0 + ni * 16;
        const float v = acc[mi][ni][j];
        if constexpr (MODE == 0) {
          Cf[(size_t)r * Nst + c] = v;
        } else {
          if (c < 2048)       Qb[(size_t)r * 2048 + c] = (bf16)v;
          else if (c < 2560)  Kb[(size_t)r * 512 + (c - 2048)] = (bf16)v;
          else                Vtb[(size_t)(c - 2560) * 4096 + r] = (bf16)v;
        }
      }
}

// ---------------------------------------------------------------- flash attention (causal GQA)
// 32x32 MFMA, swapped operands: S^T = K*Q^T (lane owns q=lane&31), O^T = V^T*P^T.
__global__ __launch_bounds__(256, 2)
void attn_fwd(const bf16* __restrict__ Q, const bf16* __restrict__ Kg_,
              const bf16* __restrict__ Vt, bf16* __restrict__ AO) {
  const int T = 2048, C = 2048, KVD = 512, MTOK = 4096;
  const int bid = blockIdx.x;
  const int qt  = (bid < 256) ? (15 - (bid >> 5)) : ((bid >> 5) - 8);  // snake balance
  const int sub = bid & 31;
  const int h = sub & 15, b = sub >> 4;
  const int kvh = h >> 2;
  const int lane = threadIdx.x & 63, w = threadIdx.x >> 6;
  const int hi = lane >> 5, lo = lane & 31;

  __shared__ __align__(16) char smem[65536];
  char* sK  = smem;          // 2 bufs x [64 rows][256 B], chunk-XOR (r&7)
  char* sVt = smem + 32768;  // 2 bufs x [128 rows][128 B], chunk-XOR (r&7)

  const bf16* Qg = Q   + (size_t)b * T * C + (size_t)h * 128;
  const bf16* Kg = Kg_ + (size_t)b * T * KVD + (size_t)kvh * 128;
  const bf16* Vg = Vt  + (size_t)kvh * 128 * MTOK + (size_t)b * T;

  const int q0 = qt * 128;
  const int qw = q0 + w * 32;

  bf16x8 qf[8];
#pragma unroll
  for (int ks = 0; ks < 8; ++ks)
    qf[ks] = *(const bf16x8*)(Qg + (size_t)(qw + lo) * C + ks * 16 + hi * 8);

  f32x16 ot[4] = {};
  float mstat = -INFINITY, lstat = 0.f;

  const int nt = 2 * qt + 2;

  auto stage = [&](int t, int buf) {
#pragma unroll
    for (int i = 0; i < 4; ++i) {
      const int ci = i * 256 + threadIdx.x;
      const int rk = ci >> 4, ck = ci & 15;
      gload_lds16(Kg + (size_t)(t * 64 + rk) * KVD + ((ck ^ (rk & 7)) * 8),
                  sK + buf * 16384 + i * 4096 + w * 1024);
      const int rv = ci >> 3, cv = ci & 7;
      gload_lds16(Vg + (size_t)rv * MTOK + t * 64 + ((cv ^ (rv & 7)) * 8),
                  sVt + buf * 16384 + i * 4096 + w * 1024);
    }
  };

  auto compute = [&](int t, int buf) {
    const int kv0 = t * 64;
    if (kv0 > qw + 31) return;
    const char* kb = sK + buf * 16384;
    const char* vb = sVt + buf * 16384;

    f32x16 sa[2] = {};
    __builtin_amdgcn_s_setprio(1);
#pragma unroll
    for (int ks = 0; ks < 8; ++ks) {
#pragma unroll
      for (int nb = 0; nb < 2; ++nb) {
        const int r = nb * 32 + lo;
        bf16x8 kf = *(const bf16x8*)(kb + (r * 256 + (((ks * 2 + hi) ^ (r & 7)) * 16)));
        sa[nb] = __builtin_amdgcn_mfma_f32_32x32x16_bf16(kf, qf[ks], sa[nb], 0, 0, 0);
      }
    }
    __builtin_amdgcn_s_setprio(0);
    if (kv0 + 63 > qw) {
      const int qg = qw + lo;
#pragma unroll
      for (int nb = 0; nb < 2; ++nb)
#pragma unroll
        for (int r = 0; r < 16; ++r) {
          const int kvg = kv0 + nb * 32 + (r & 3) + 8 * (r >> 2) + 4 * hi;
          if (kvg > qg) sa[nb][r] = -1e30f;
        }
    }
    float pm = -INFINITY;
#pragma unroll
    for (int nb = 0; nb < 2; ++nb)
#pragma unroll
      for (int r = 0; r < 16; ++r) pm = fmaxf(pm, sa[nb][r]);
    pm = fmaxf(pm, __shfl_xor(pm, 32));

    if (__any(pm > mstat + 8.f)) {           // defer-max (T13)
      const float mn = fmaxf(mstat, pm);
      const float rs = __expf(mstat - mn);
      mstat = mn;
      lstat *= rs;
#pragma unroll
      for (int db = 0; db < 4; ++db)
#pragma unroll
        for (int r = 0; r < 16; ++r) ot[db][r] *= rs;
    }

    float ls = 0.f;
    unsigned int pw[2][8];
#pragma unroll
    for (int nb = 0; nb < 2; ++nb)
#pragma unroll
      for (int j = 0; j < 8; ++j) {
        const float e0 = __expf(sa[nb][2 * j]     - mstat);
        const float e1 = __expf(sa[nb][2 * j + 1] - mstat);
        ls += e0 + e1;
        pw[nb][j] = packbf(e0, e1);
      }
    ls += __shfl_xor(ls, 32);
    lstat += ls;

#pragma unroll
    for (int nb = 0; nb < 2; ++nb) {
      unsigned int pj[8];
#pragma unroll
      for (int j = 0; j < 8; ++j) pj[j] = __shfl_xor(pw[nb][j], 32);
      __builtin_amdgcn_s_setprio(1);
#pragma unroll
      for (int half = 0; half < 2; ++half) {
        const int x = half * 4;
        uint32x4 bw;
        bw[0] = hi ? pj[x + 2] : pw[nb][x + 0];
        bw[1] = hi ? pj[x + 3] : pw[nb][x + 1];
        bw[2] = hi ? pw[nb][x + 2] : pj[x + 0];
        bw[3] = hi ? pw[nb][x + 3] : pj[x + 1];
        const bf16x8 pb = __builtin_bit_cast(bf16x8, bw);
        const int ks = nb * 2 + half;
#pragma unroll
        for (int db = 0; db < 4; ++db) {
          const int rv = db * 32 + lo;
          bf16x8 vf = *(const bf16x8*)(vb + (rv * 128 + (((ks * 2 + hi) ^ (rv & 7)) * 16)));
          ot[db] = __builtin_amdgcn_mfma_f32_32x32x16_bf16(vf, pb, ot[db], 0, 0, 0);
        }
      }
      __builtin_amdgcn_s_setprio(0);
    }
  };

  stage(0, 0);
  for (int t = 0; t < nt - 1; ++t) {
    stage(t + 1, (t + 1) & 1);
    asm volatile("s_waitcnt vmcnt(8)" ::: "memory");
    __builtin_amdgcn_s_barrier();
    compute(t, t & 1);
    __builtin_amdgcn_s_barrier();
  }
  asm volatile("s_waitcnt vmcnt(0)" ::: "memory");
  __builtin_amdgcn_s_barrier();
  compute(nt - 1, (nt - 1) & 1);

  __syncthreads();
  char* sO = smem;
  const float inv = 1.f / lstat;
  const int lq = w * 32 + lo;
#pragma unroll
  for (int db = 0; db < 4; ++db) {
#pragma unroll
    for (int j = 0; j < 8; ++j) {
      const int r = 2 * j;
      const int d = db * 32 + (r & 3) + 8 * (r >> 2) + 4 * hi;
      const unsigned int pv = packbf(ot[db][r] * inv, ot[db][r + 1] * inv);
      *(unsigned int*)(sO + (lq * 256 + ((2 * d) ^ (16 * (lq & 7))))) = pv;
    }
  }
  __syncthreads();
  bf16* Og = AO + (size_t)b * T * C + (size_t)h * 128;
#pragma unroll
  for (int i = 0; i < 8; ++i) {
    const int cid = i * 256 + threadIdx.x;
    const int rq = cid >> 4, c = cid & 15;
    bf16x8 vv = *(const bf16x8*)(sO + (rq * 256 + ((c * 16) ^ (16 * (rq & 7)))));
    *(bf16x8*)(Og + (size_t)(q0 + rq) * C + c * 8) = vv;
  }
}

// ---------------------------------------------------------------- launch
extern "C" void kernel_launch(void* const* d_in, const int* in_sizes, int n_in,
                              void* d_out, int out_size, void* d_ws, size_t ws_size,
                              hipStream_t stream) {
  const float* x  = (const float*)d_in[0];
  const float* Wq = (const float*)d_in[1];
  const float* Wk = (const float*)d_in[2];
  const float* Wv = (const float*)d_in[3];
  const float* Wo = (const float*)d_in[4];
  float* out = (float*)d_out;

  char* ws = (char*)d_ws;
  bf16* xb   = (bf16*)(ws);                   // 16,777,216 B
  bf16* wqkv = (bf16*)(ws + 16777216);        // 12,582,912  [3072][2048]
  bf16* wob  = (bf16*)(ws + 29360128);        //  8,388,608
  bf16* Qb   = (bf16*)(ws + 37748736);        // 16,777,216
  bf16* Kb   = (bf16*)(ws + 54525952);        //  4,194,304
  bf16* Vtb  = (bf16*)(ws + 58720256);        //  4,194,304  ([512][4096])
  bf16* AOb  = (bf16*)(ws + 62914560);        // 16,777,216

  const float scale = 0.08838834764831845f;   // 128^-0.5, folded into Wq
  cvt_all<<<2048, 256, 0, stream>>>(x, Wq, Wk, Wv, Wo, xb, wqkv, wob, scale);

  gemm128<1><<<dim3(24, 32), 256, 0, stream>>>(xb, wqkv, nullptr, Qb, Kb, Vtb, 2048, 0);

  attn_fwd<<<512, 256, 0, stream>>>(Qb, Kb, Vtb, AOb);

  gemm128<0><<<dim3(16, 32), 256, 0, stream>>>(AOb, wob, out, nullptr, nullptr, nullptr, 2048, 2048);
}